// Round 1
// baseline (706.100 us; speedup 1.0000x reference)
//
#include <hip/hip_runtime.h>

#define N_DATA     131072
#define D_VECTOR   128
#define N_SUB      8
#define D_SUB      16
#define N_CLUSTERS 256
#define N_CODEBOOKS 64

typedef float v2f __attribute__((ext_vector_type(2)));

// ws layout in 4-byte words (~3.2 MB base; +4 MB optional xn8 region if ws permits)
#define WS_LABELS 0
#define WS_PERM   (N_DATA)
#define WS_CNT    (2*N_DATA)
#define WS_CURSOR (2*N_DATA + 64)
#define WS_OFF    (2*N_DATA + 128)
#define WS_CNORM  (2*N_DATA + 256)                  // 131072 floats, numpy-order fp32
#define WS_CNSEL  (2*N_DATA + 256 + N_CODEBOOKS*N_SUB*N_CLUSTERS)
#define WS_CODES  (WS_CNSEL + 64)                   // 131072*8 bytes = 262144 words
#define WS_XNORM  (WS_CODES + 262144)               // 131072 floats
#define WS_XN8    (WS_XNORM + N_DATA)               // optional: 131072*8 floats per-(n,s) norms

// ---------------------------------------------------------------- precompute
// np.sum(cb*cb, axis=2) / np.sum(sel*sel, axis=0): sequential d, separate mul/add.
__global__ __launch_bounds__(256) void pq_precompute(
    const float* __restrict__ cb, const float* __restrict__ sel,
    float* __restrict__ cnorm_cb, float* __restrict__ cnorm_sel,
    int* __restrict__ cnt)
{
    int idx = blockIdx.x * 256 + threadIdx.x;       // 0..131071 = (l*8+s)*256+k
    int row = idx >> 8;
    int k   = idx & 255;
    const float* p = cb + (size_t)row * (D_SUB * N_CLUSTERS) + k;
    float sum = 0.f;
#pragma unroll
    for (int d = 0; d < D_SUB; d++) {
        float v = p[(size_t)d * N_CLUSTERS];
        sum = __fadd_rn(sum, __fmul_rn(v, v));
    }
    cnorm_cb[idx] = sum;
    if (idx < N_CODEBOOKS) {
        float s2 = 0.f;
        for (int d = 0; d < D_VECTOR; d++) {
            float v = sel[d * N_CODEBOOKS + idx];
            s2 = __fadd_rn(s2, __fmul_rn(v, v));
        }
        cnorm_sel[idx] = s2;
        cnt[idx] = 0;
    }
}

// ---------------------------------------------------------------- transpose + xnorm
// Reads x [d][n] coalesced, writes xt[n][d] (row per thread) + xnorm[n]
// (numpy strided reduction: sequential d, separate mul/add).
// If xn8 != null, also writes per-(n,s) subvector norms (bit-identical op order
// to what pq_encode would compute: sequential over the 16 d's of the subvector).
__global__ __launch_bounds__(256, 2) void pq_transpose(
    const float* __restrict__ x, float* __restrict__ xt, float* __restrict__ xnorms,
    float* __restrict__ xn8)
{
    int n = blockIdx.x * 256 + threadIdx.x;
    float xm[D_VECTOR];
#pragma unroll
    for (int d = 0; d < D_VECTOR; d++) xm[d] = x[(size_t)d * N_DATA + n];  // coalesced

    float4* dst = (float4*)(xt + (size_t)n * D_VECTOR);
#pragma unroll
    for (int i = 0; i < D_VECTOR / 4; i++)
        dst[i] = make_float4(xm[4*i], xm[4*i+1], xm[4*i+2], xm[4*i+3]);

    float xn = 0.f;
#pragma unroll
    for (int d = 0; d < D_VECTOR; d++) xn = __fadd_rn(xn, __fmul_rn(xm[d], xm[d]));
    xnorms[n] = xn;

    if (xn8) {
        float xns[N_SUB];
#pragma unroll
        for (int ss = 0; ss < N_SUB; ss++) {
            float v = 0.f;
#pragma unroll
            for (int d = 0; d < D_SUB; d++) {
                float t = xm[ss * D_SUB + d];
                v = __fadd_rn(v, __fmul_rn(t, t));
            }
            xns[ss] = v;
        }
        float4* q = (float4*)(xn8 + (size_t)n * N_SUB);
        q[0] = make_float4(xns[0], xns[1], xns[2], xns[3]);
        q[1] = make_float4(xns[4], xns[5], xns[6], xns[7]);
    }
}

// ---------------------------------------------------------------- stage 1: labels
__global__ __launch_bounds__(256, 4) void pq_labels2(
    const float* __restrict__ x, const float* __restrict__ sel,
    const float* __restrict__ cnorm_sel, const float* __restrict__ xnorms,
    int* __restrict__ labels, int* __restrict__ cnt)
{
    __shared__ int hist[N_CODEBOOKS];
    int tid = threadIdx.x;
    if (tid < N_CODEBOOKS) hist[tid] = 0;
    __syncthreads();

    int n = blockIdx.x * 256 + tid;

    v2f acc[32];
#pragma unroll
    for (int lp = 0; lp < 32; lp++) acc[lp] = (v2f){0.f, 0.f};

    for (int d = 0; d < D_VECTOR; d++) {
        float xv = x[(size_t)d * N_DATA + n];        // coalesced
        v2f xv2 = (v2f){xv, xv};
        const v2f* sp = (const v2f*)(sel + d * N_CODEBOOKS);  // uniform
#pragma unroll
        for (int lp = 0; lp < 32; lp++)
            acc[lp] = __builtin_elementwise_fma(xv2, sp[lp], acc[lp]);  // v_pk_fma_f32
    }

    float xn = xnorms[n];
    float best = 1e30f;
    int   bl = 0;
#pragma unroll
    for (int lp = 0; lp < 32; lp++) {
        float dx = __fadd_rn(__fsub_rn(xn, __fmul_rn(2.0f, acc[lp].x)), cnorm_sel[2*lp]);
        float dy = __fadd_rn(__fsub_rn(xn, __fmul_rn(2.0f, acc[lp].y)), cnorm_sel[2*lp + 1]);
        if (dx < best) { best = dx; bl = 2*lp; }
        if (dy < best) { best = dy; bl = 2*lp + 1; }
    }
    labels[n] = bl;
    atomicAdd(&hist[bl], 1);
    __syncthreads();
    if (tid < N_CODEBOOKS) atomicAdd(&cnt[tid], hist[tid]);
}

// ---------------------------------------------------------------- scan (1 wave)
__global__ void pq_scan(const int* __restrict__ cnt, int* __restrict__ off, int* __restrict__ cursor)
{
    int tid = threadIdx.x;
    int v = cnt[tid];
    int inc = v;
#pragma unroll
    for (int sft = 1; sft < 64; sft <<= 1) {
        int o = __shfl_up(inc, sft, 64);
        if (tid >= sft) inc += o;
    }
    int exc = inc - v;
    off[tid] = exc;
    cursor[tid] = exc;
    if (tid == 63) off[64] = inc;
}

// ---------------------------------------------------------------- counting-sort scatter
// perm entries are PACKED: (n << 6) | label  (n < 2^17, label < 64)
__global__ __launch_bounds__(256) void pq_scatter(
    const int* __restrict__ labels, int* __restrict__ cursor, int* __restrict__ perm)
{
    __shared__ int lcnt[N_CODEBOOKS];
    __shared__ int lbase[N_CODEBOOKS];
    int tid = threadIdx.x;
    if (tid < N_CODEBOOKS) lcnt[tid] = 0;
    __syncthreads();
    int base = blockIdx.x * 1024;
    int lv[4], slot[4];
#pragma unroll
    for (int i = 0; i < 4; i++) {
        int n = base + i * 256 + tid;
        int l = labels[n];
        lv[i] = l;
        slot[i] = atomicAdd(&lcnt[l], 1);
    }
    __syncthreads();
    if (tid < N_CODEBOOKS) lbase[tid] = atomicAdd(&cursor[tid], lcnt[tid]);
    __syncthreads();
#pragma unroll
    for (int i = 0; i < 4; i++) {
        int n = base + i * 256 + tid;
        perm[lbase[lv[i]] + slot[i]] = (n << 6) | lv[i];
    }
}

// DPP min step: v = min(v, v_from_lane(ctrl)). Invalid-source lanes keep v (old).
template<int CTRL>
__device__ __forceinline__ float dppmin(float v)
{
    int t = __builtin_amdgcn_update_dpp(__float_as_int(v), __float_as_int(v),
                                        CTRL, 0xF, 0xF, false);
    return fminf(v, __int_as_float(t));
}

// ---------------------------------------------------------------- stage 2: PQ encode v5
// Wave = one point at a time; lane L holds clusters [4L,4L+4) x 16 d in VGPRs
// (reloaded only on label change). Distance arithmetic is UNCHANGED from v4
// (packed fp32 mul/add, contract off -> numpy bit-exact). Changes vs v4:
//  - perm is packed (n<<6)|l: one wave-uniform load instead of two dependent ones
//  - x row double-buffered, packed-word prefetched 2 deep (unroll 2 keeps the
//    buffer index compile-time -> registers, not scratch)
//  - optional precomputed per-(n,s) xnorm (bit-identical op order) if ws permits
//  - float-compare argmin (NaN-free; +/-0 compare equal both paths) replaces the
//    ordered-uint fkey mapping; strict-< / ==-priority keeps numpy first-tie
//  - cross-lane min via DPP (row_shr 1/2/4/8, row_bcast 15/31 -> lane 63) +
//    readlane: 12 cheap VALU insts instead of 6 dependent ds_bpermute shuffles
//  - codes accumulated per-lane via cndmask, one scattered byte store per wave
template<bool PRE>
__global__ __launch_bounds__(256, 4) void pq_encode_t(
    const float* __restrict__ xt, const float* __restrict__ cb,
    const float* __restrict__ cnorm_cb, const float* __restrict__ xn8,
    const unsigned int* __restrict__ perm, unsigned char* __restrict__ codes)
{
    int tid  = threadIdx.x;
    int lane = tid & 63;
    int w    = tid >> 6;
    int s    = blockIdx.x & 7;
    int seg  = blockIdx.x >> 3;
    int base = seg * 256 + w * 64;

    int lcur = -1;
    v2f cbA[D_SUB], cbB[D_SUB];
    v2f cnA = (v2f){0.f, 0.f}, cnB = (v2f){0.f, 0.f};

    int mycode = 0, myn = 0;

    // pipeline prologue: packed word + x row for point 0; packed word for point 1
    unsigned pkc = perm[base];
    int nc = (int)(pkc >> 6), lc = (int)(pkc & 63u);
    float4 xbuf[2][4];
    float  xnbuf[2];
    {
        const float4* xp = (const float4*)(xt + (size_t)nc * D_VECTOR + s * D_SUB);
        xbuf[0][0] = xp[0]; xbuf[0][1] = xp[1]; xbuf[0][2] = xp[2]; xbuf[0][3] = xp[3];
        if (PRE) xnbuf[0] = xn8[((size_t)nc << 3) | s];
    }
    unsigned pkn = perm[base + 1];

#pragma unroll 2
    for (int i = 0; i < 64; i++) {
        const int cur = i & 1;
        const int nxt = cur ^ 1;
        int n = nc, l = lc;

        // decode next point's packed word; issue its x (+xn) loads a full
        // iteration ahead; fetch the packed word for i+2 (reads past the last
        // segment land in the adjacent ws region -> harmless)
        int n1 = (int)(pkn >> 6), l1 = (int)(pkn & 63u);
        if (i < 63) {
            const float4* xq = (const float4*)(xt + (size_t)n1 * D_VECTOR + s * D_SUB);
            xbuf[nxt][0] = xq[0]; xbuf[nxt][1] = xq[1];
            xbuf[nxt][2] = xq[2]; xbuf[nxt][3] = xq[3];
            if (PRE) xnbuf[nxt] = xn8[((size_t)n1 << 3) | s];
        }
        if (i < 62) pkn = perm[base + i + 2];
        nc = n1; lc = l1;

        if (l != lcur) {                   // uniform branch; ~1-2x per 64 points
            lcur = l;
            const float* cbs = cb + (size_t)(l * N_SUB + s) * (D_SUB * N_CLUSTERS);
#pragma unroll
            for (int d = 0; d < D_SUB; d++) {
                float4 v = *(const float4*)(cbs + (size_t)d * N_CLUSTERS + lane * 4);
                cbA[d] = (v2f){v.x, v.y};
                cbB[d] = (v2f){v.z, v.w};
            }
            float4 c = *(const float4*)(cnorm_cb + (size_t)(l * N_SUB + s) * N_CLUSTERS + lane * 4);
            cnA = (v2f){c.x, c.y};
            cnB = (v2f){c.z, c.w};
        }

        float4 x0 = xbuf[cur][0], x1 = xbuf[cur][1], x2 = xbuf[cur][2], x3 = xbuf[cur][3];
        float xs[D_SUB] = { x0.x, x0.y, x0.z, x0.w, x1.x, x1.y, x1.z, x1.w,
                            x2.x, x2.y, x2.z, x2.w, x3.x, x3.y, x3.z, x3.w };

        // xnorm: numpy strided reduction (sequential d, separate mul/add);
        // PRE path loads the bit-identical precomputed value instead.
        float xn;
        if (PRE) {
            xn = xnbuf[cur];
        } else {
            xn = 0.f;
#pragma unroll
            for (int d = 0; d < D_SUB; d++) xn = __fadd_rn(xn, __fmul_rn(xs[d], xs[d]));
        }

        v2f a0 = (v2f){0.f, 0.f}, a1 = (v2f){0.f, 0.f};
        float m; int j;
        {
#pragma clang fp contract(off)
#pragma unroll
            for (int d = 0; d < D_SUB; d++) {
                v2f xv = (v2f){xs[d], xs[d]};
                a0 = a0 + xv * cbA[d];     // v_pk_mul_f32 + v_pk_add_f32, exact
                a1 = a1 + xv * cbB[d];
            }
            v2f xnv = (v2f){xn, xn};
            v2f twov = (v2f){2.f, 2.f};
            v2f d0 = (xnv - twov * a0) + cnA;   // ((xn - 2*acc) + cn), rounded per op
            v2f d1 = (xnv - twov * a1) + cnB;

            // per-lane min of 4 with numpy first-tie (== priority low j; +/-0 equal)
            m = fminf(fminf(d0.x, d0.y), fminf(d1.x, d1.y));
            j = (d1.x == m) ? 2 : 3;
            j = (d0.y == m) ? 1 : j;
            j = (d0.x == m) ? 0 : j;
        }

        // cross-lane min via DPP: after shr 1/2/4/8 lane15 of each row holds the
        // row min; bcast15 merges row pairs, bcast31 merges halves -> lane 63.
        float g = m;
        g = dppmin<0x111>(g);   // row_shr:1
        g = dppmin<0x112>(g);   // row_shr:2
        g = dppmin<0x114>(g);   // row_shr:4
        g = dppmin<0x118>(g);   // row_shr:8
        g = dppmin<0x142>(g);   // row_bcast:15
        g = dppmin<0x143>(g);   // row_bcast:31
        float gmin = __int_as_float(__builtin_amdgcn_readlane(__float_as_int(g), 63));

        unsigned long long bal = __ballot(m == gmin);
        int winner = (int)(__ffsll((long long)bal) - 1);   // lowest lane = lowest k
        int myk = (lane << 2) | j;
        int kwin = __builtin_amdgcn_readlane(myk, winner); // uniform
        bool selp = (lane == i);
        mycode = selp ? kwin : mycode;
        myn    = selp ? n    : myn;
    }
    codes[((size_t)myn << 3) | s] = (unsigned char)mycode;
}

// ---------------------------------------------------------------- decode: coalesced out writes
__global__ __launch_bounds__(256) void pq_decode(
    const float* __restrict__ cb, const int* __restrict__ labels,
    const unsigned char* __restrict__ codes, float* __restrict__ out)
{
    int s = blockIdx.x & 7;
    int n = (blockIdx.x >> 3) * 256 + threadIdx.x;
    int l = labels[n];
    int k = codes[(size_t)n * N_SUB + s];
    const float* base = cb + ((size_t)(l * N_SUB + s) * D_SUB) * N_CLUSTERS + k;
#pragma unroll
    for (int dd = 0; dd < D_SUB; dd++)
        out[(size_t)(s * D_SUB + dd) * N_DATA + n] = base[(size_t)dd * N_CLUSTERS];
}

// ---------------------------------------------------------------- launcher
extern "C" void kernel_launch(void* const* d_in, const int* in_sizes, int n_in,
                              void* d_out, int out_size, void* d_ws, size_t ws_size,
                              hipStream_t stream)
{
    (void)in_sizes; (void)n_in; (void)out_size;
    const float* x   = (const float*)d_in[0];
    const float* cb  = (const float*)d_in[1];
    const float* sel = (const float*)d_in[2];
    float* out = (float*)d_out;

    int*   wsi    = (int*)d_ws;
    float* wsf    = (float*)d_ws;
    int*   labels = wsi + WS_LABELS;
    int*   perm   = wsi + WS_PERM;
    int*   cnt    = wsi + WS_CNT;
    int*   cursor = wsi + WS_CURSOR;
    int*   off    = wsi + WS_OFF;
    float* cnorm  = wsf + WS_CNORM;
    float* cnsel  = wsf + WS_CNSEL;
    unsigned char* codes = (unsigned char*)(wsi + WS_CODES);
    float* xnorms = wsf + WS_XNORM;

    // per-(n,s) xnorm precompute only if the workspace is big enough
    bool pre = ws_size >= (size_t)(WS_XN8 + (size_t)N_DATA * N_SUB) * 4u;
    float* xn8 = pre ? (wsf + WS_XN8) : (float*)nullptr;

    float* xt = out;   // d_out doubles as transpose scratch; pq_decode overwrites it fully

    hipLaunchKernelGGL(pq_precompute, dim3(512), dim3(256), 0, stream, cb, sel, cnorm, cnsel, cnt);
    hipLaunchKernelGGL(pq_transpose, dim3(N_DATA / 256), dim3(256), 0, stream, x, xt, xnorms, xn8);
    hipLaunchKernelGGL(pq_labels2, dim3(N_DATA / 256), dim3(256), 0, stream, x, sel, cnsel, xnorms, labels, cnt);
    hipLaunchKernelGGL(pq_scan, dim3(1), dim3(64), 0, stream, cnt, off, cursor);
    hipLaunchKernelGGL(pq_scatter, dim3(N_DATA / 1024), dim3(256), 0, stream, labels, cursor, perm);
    if (pre)
        hipLaunchKernelGGL((pq_encode_t<true>),  dim3((N_DATA / 256) * N_SUB), dim3(256), 0, stream,
                           xt, cb, cnorm, xn8, (const unsigned int*)perm, codes);
    else
        hipLaunchKernelGGL((pq_encode_t<false>), dim3((N_DATA / 256) * N_SUB), dim3(256), 0, stream,
                           xt, cb, cnorm, (const float*)nullptr, (const unsigned int*)perm, codes);
    hipLaunchKernelGGL(pq_decode, dim3((N_DATA / 256) * N_SUB), dim3(256), 0, stream, cb, labels, codes, out);
}

// Round 2
// 453.963 us; speedup vs baseline: 1.5554x; 1.5554x over previous
//
#include <hip/hip_runtime.h>

#define N_DATA     131072
#define D_VECTOR   128
#define N_SUB      8
#define D_SUB      16
#define N_CLUSTERS 256
#define N_CODEBOOKS 64

typedef float v2f __attribute__((ext_vector_type(2)));

// ws layout in 4-byte words (~2.6 MB total; cbT lives in d_out, which pq_decode
// fully overwrites afterwards)
#define WS_LABELS 0
#define WS_PERM   (N_DATA)
#define WS_CNT    (2*N_DATA)
#define WS_CURSOR (2*N_DATA + 64)
#define WS_OFF    (2*N_DATA + 128)
#define WS_CNORM  (2*N_DATA + 256)                  // 131072 floats, numpy-order fp32
#define WS_CNSEL  (WS_CNORM + N_CODEBOOKS*N_SUB*N_CLUSTERS)
#define WS_CODES  (WS_CNSEL + 64)                   // 131072*8 bytes = 262144 words

// ---------------------------------------------------------------- precompute
// cnorm = np.sum(cb*cb, axis=2) (sequential d, separate mul/add), plus a
// pair-interleaved transposed codebook for the encode stage:
//   cbT[row][k>>1][d][k&1] = cb[row][d][k]   (row = l*8+s)
// so encode can s_load 32 consecutive floats per k-pair and feed v_pk ops.
__global__ __launch_bounds__(256) void pq_precompute(
    const float* __restrict__ cb, const float* __restrict__ sel,
    float* __restrict__ cnorm_cb, float* __restrict__ cnorm_sel,
    float* __restrict__ cbT, int* __restrict__ cnt)
{
    int row = blockIdx.x;                 // 0..511 = l*8+s
    int k   = threadIdx.x;                // 0..255
    const float* p  = cb  + (size_t)row * (D_SUB * N_CLUSTERS) + k;
    float*       ct = cbT + ((size_t)row << 12) + ((size_t)(k >> 1) << 5) + (k & 1);
    float sum = 0.f;
#pragma unroll
    for (int d = 0; d < D_SUB; d++) {
        float v = p[(size_t)d * N_CLUSTERS];
        ct[d << 1] = v;
        sum = __fadd_rn(sum, __fmul_rn(v, v));
    }
    int idx = row * 256 + k;
    cnorm_cb[idx] = sum;
    if (idx < N_CODEBOOKS) {
        float s2 = 0.f;
        for (int d = 0; d < D_VECTOR; d++) {
            float v = sel[d * N_CODEBOOKS + idx];
            s2 = __fadd_rn(s2, __fmul_rn(v, v));
        }
        cnorm_sel[idx] = s2;
        cnt[idx] = 0;
    }
}

// ---------------------------------------------------------------- stage 1: labels
// d = xnorm - 2*(x.T@sel) + cnorm, argmin axis=1. xnorm computed inline with
// the numpy strided-reduction order (sequential d, separate mul/add).
__global__ __launch_bounds__(256, 4) void pq_labels2(
    const float* __restrict__ x, const float* __restrict__ sel,
    const float* __restrict__ cnorm_sel,
    int* __restrict__ labels, int* __restrict__ cnt)
{
    __shared__ int hist[N_CODEBOOKS];
    int tid = threadIdx.x;
    if (tid < N_CODEBOOKS) hist[tid] = 0;
    __syncthreads();

    int n = blockIdx.x * 256 + tid;

    v2f acc[32];
#pragma unroll
    for (int lp = 0; lp < 32; lp++) acc[lp] = (v2f){0.f, 0.f};

    float xn = 0.f;
    for (int d = 0; d < D_VECTOR; d++) {
        float xv = x[(size_t)d * N_DATA + n];        // coalesced
        xn = __fadd_rn(xn, __fmul_rn(xv, xv));       // sequential d: numpy-exact
        v2f xv2 = (v2f){xv, xv};
        const v2f* sp = (const v2f*)(sel + d * N_CODEBOOKS);  // uniform
#pragma unroll
        for (int lp = 0; lp < 32; lp++)
            acc[lp] = __builtin_elementwise_fma(xv2, sp[lp], acc[lp]);  // v_pk_fma_f32
    }

    float best = 1e30f;
    int   bl = 0;
#pragma unroll
    for (int lp = 0; lp < 32; lp++) {
        float dx = __fadd_rn(__fsub_rn(xn, __fmul_rn(2.0f, acc[lp].x)), cnorm_sel[2*lp]);
        float dy = __fadd_rn(__fsub_rn(xn, __fmul_rn(2.0f, acc[lp].y)), cnorm_sel[2*lp + 1]);
        if (dx < best) { best = dx; bl = 2*lp; }
        if (dy < best) { best = dy; bl = 2*lp + 1; }
    }
    labels[n] = bl;
    atomicAdd(&hist[bl], 1);
    __syncthreads();
    if (tid < N_CODEBOOKS) atomicAdd(&cnt[tid], hist[tid]);
}

// ---------------------------------------------------------------- scan (1 wave)
__global__ void pq_scan(const int* __restrict__ cnt, int* __restrict__ off, int* __restrict__ cursor)
{
    int tid = threadIdx.x;
    int v = cnt[tid];
    int inc = v;
#pragma unroll
    for (int sft = 1; sft < 64; sft <<= 1) {
        int o = __shfl_up(inc, sft, 64);
        if (tid >= sft) inc += o;
    }
    int exc = inc - v;
    off[tid] = exc;
    cursor[tid] = exc;
    if (tid == 63) off[64] = inc;
}

// ---------------------------------------------------------------- counting-sort scatter
// perm entries are PACKED: (n << 6) | label  (n < 2^17, label < 64)
__global__ __launch_bounds__(256) void pq_scatter(
    const int* __restrict__ labels, int* __restrict__ cursor, int* __restrict__ perm)
{
    __shared__ int lcnt[N_CODEBOOKS];
    __shared__ int lbase[N_CODEBOOKS];
    int tid = threadIdx.x;
    if (tid < N_CODEBOOKS) lcnt[tid] = 0;
    __syncthreads();
    int base = blockIdx.x * 1024;
    int lv[4], slot[4];
#pragma unroll
    for (int i = 0; i < 4; i++) {
        int n = base + i * 256 + tid;
        int l = labels[n];
        lv[i] = l;
        slot[i] = atomicAdd(&lcnt[l], 1);
    }
    __syncthreads();
    if (tid < N_CODEBOOKS) lbase[tid] = atomicAdd(&cursor[tid], lcnt[tid]);
    __syncthreads();
#pragma unroll
    for (int i = 0; i < 4; i++) {
        int n = base + i * 256 + tid;
        perm[lbase[lv[i]] + slot[i]] = (n << 6) | lv[i];
    }
}

// ---------------------------------------------------------------- stage 2: PQ encode v6
// Lane = one point (perm-sorted). The codebook is wave-uniform: the label of
// the wave's points is (almost always) a single value, so codebook reads are
// scalar loads broadcast to all lanes, and each lane scans k = 0..255 locally.
// Rare label-boundary waves run a masked multi-pass (one pass per distinct
// label; points are sorted so passes are ~1.03 on average).
// Arithmetic per (point,k) is unchanged from v4/v5: sequential-d separate
// mul/add (contract off), dist = (xn - 2*acc) + cn, ascending-k strict-< argmin
// == numpy first-occurrence. Distances are NaN-free so float compare is exact.
__global__ __launch_bounds__(256, 4) void pq_encode6(
    const float* __restrict__ x, const float* __restrict__ cbT,
    const float* __restrict__ cnorm_cb, const unsigned int* __restrict__ perm,
    unsigned char* __restrict__ codes)
{
    int tid = threadIdx.x;
    int s   = blockIdx.x & 7;
    int pos = (blockIdx.x >> 3) * 256 + tid;
    unsigned pk = perm[pos];
    int n = (int)(pk >> 6);
    int l = (int)(pk & 63u);

    // gather this point's 16 subvector components from the original [d][n] layout
    float xs[D_SUB];
#pragma unroll
    for (int d = 0; d < D_SUB; d++)
        xs[d] = x[(size_t)(s * D_SUB + d) * N_DATA + n];

    // xnorm: numpy strided reduction (sequential d, separate mul/add)
    float xn = 0.f;
#pragma unroll
    for (int d = 0; d < D_SUB; d++)
        xn = __fadd_rn(xn, __fmul_rn(xs[d], xs[d]));

    v2f xs2[D_SUB];
#pragma unroll
    for (int d = 0; d < D_SUB; d++) xs2[d] = (v2f){xs[d], xs[d]};
    const v2f xnv  = (v2f){xn, xn};
    const v2f twov = (v2f){2.f, 2.f};

    int bestk = 0;
    bool done = false;
    while (true) {
        unsigned long long todo = __ballot(!done);
        if (!todo) break;
        int src  = (int)(__ffsll((long long)todo) - 1);
        int lcur = __builtin_amdgcn_readlane(l, src);      // uniform label for this pass

        const float* cbs = cbT      + ((size_t)(lcur * N_SUB + s) << 12);  // uniform
        const float* cns = cnorm_cb + ((size_t)(lcur * N_SUB + s) << 8);   // uniform

        float bb = 1e30f; int bbk = 0;
        {
#pragma clang fp contract(off)
#pragma unroll 2
            for (int kkp = 0; kkp < N_CLUSTERS / 2; kkp++) {
                const v2f* cp = (const v2f*)(cbs + (kkp << 5));  // 32 floats: pair {2kp,2kp+1} x 16 d
                v2f acc = (v2f){0.f, 0.f};
#pragma unroll
                for (int d = 0; d < D_SUB; d++)
                    acc = acc + xs2[d] * cp[d];          // v_pk_mul + v_pk_add, exact
                v2f dist = (xnv - twov * acc) + *(const v2f*)(cns + (kkp << 1));
                if (dist.x < bb) { bb = dist.x; bbk = (kkp << 1); }
                if (dist.y < bb) { bb = dist.y; bbk = (kkp << 1) | 1; }
            }
        }
        if (!done && l == lcur) { bestk = bbk; done = true; }
    }
    codes[((size_t)n << 3) | s] = (unsigned char)bestk;
}

// ---------------------------------------------------------------- decode: coalesced out writes
__global__ __launch_bounds__(256) void pq_decode(
    const float* __restrict__ cb, const int* __restrict__ labels,
    const unsigned char* __restrict__ codes, float* __restrict__ out)
{
    int s = blockIdx.x & 7;
    int n = (blockIdx.x >> 3) * 256 + threadIdx.x;
    int l = labels[n];
    int k = codes[(size_t)n * N_SUB + s];
    const float* base = cb + ((size_t)(l * N_SUB + s) * D_SUB) * N_CLUSTERS + k;
#pragma unroll
    for (int dd = 0; dd < D_SUB; dd++)
        out[(size_t)(s * D_SUB + dd) * N_DATA + n] = base[(size_t)dd * N_CLUSTERS];
}

// ---------------------------------------------------------------- launcher
extern "C" void kernel_launch(void* const* d_in, const int* in_sizes, int n_in,
                              void* d_out, int out_size, void* d_ws, size_t ws_size,
                              hipStream_t stream)
{
    (void)in_sizes; (void)n_in; (void)out_size; (void)ws_size;
    const float* x   = (const float*)d_in[0];
    const float* cb  = (const float*)d_in[1];
    const float* sel = (const float*)d_in[2];
    float* out = (float*)d_out;

    int*   wsi    = (int*)d_ws;
    float* wsf    = (float*)d_ws;
    int*   labels = wsi + WS_LABELS;
    int*   perm   = wsi + WS_PERM;
    int*   cnt    = wsi + WS_CNT;
    int*   cursor = wsi + WS_CURSOR;
    int*   off    = wsi + WS_OFF;
    float* cnorm  = wsf + WS_CNORM;
    float* cnsel  = wsf + WS_CNSEL;
    unsigned char* codes = (unsigned char*)(wsi + WS_CODES);

    // transposed pair-interleaved codebook (8 MB) lives in d_out; pq_decode
    // fully overwrites d_out afterwards.
    float* cbT = out;

    hipLaunchKernelGGL(pq_precompute, dim3(512), dim3(256), 0, stream, cb, sel, cnorm, cnsel, cbT, cnt);
    hipLaunchKernelGGL(pq_labels2, dim3(N_DATA / 256), dim3(256), 0, stream, x, sel, cnsel, labels, cnt);
    hipLaunchKernelGGL(pq_scan, dim3(1), dim3(64), 0, stream, cnt, off, cursor);
    hipLaunchKernelGGL(pq_scatter, dim3(N_DATA / 1024), dim3(256), 0, stream, labels, cursor, perm);
    hipLaunchKernelGGL(pq_encode6, dim3((N_DATA / 256) * N_SUB), dim3(256), 0, stream,
                       x, cbT, cnorm, (const unsigned int*)perm, codes);
    hipLaunchKernelGGL(pq_decode, dim3((N_DATA / 256) * N_SUB), dim3(256), 0, stream, cb, labels, codes, out);
}